// Round 3
// baseline (385.257 us; speedup 1.0000x reference)
//
#include <hip/hip_runtime.h>
#include <hip/hip_bf16.h>

#define NN 50000     // nodes
#define NR 4         // relations
#define NE 160000    // edges per relation
#define HD 128       // hidden dim
#define OD 100       // out dim
#define NQ 8192      // queries
#define NB_SCAN 196  // 196*256 >= NN
#define MT 64        // GEMM M tile
#define KSTEPS 10    // 640 / 64

typedef __attribute__((ext_vector_type(8))) short bf16x8;
typedef __attribute__((ext_vector_type(4))) float f32x4;
typedef __attribute__((ext_vector_type(4))) int int4v;

static __device__ __forceinline__ unsigned short f2bf(float f) {
    union { float f; unsigned int u; } v; v.f = f;
    unsigned int u = v.u;
    unsigned int r = u + 0x7FFFu + ((u >> 16) & 1u);   // RNE
    return (unsigned short)(r >> 16);
}
static __device__ __forceinline__ float bflo(unsigned int v) {
    union { unsigned int u; float f; } x; x.u = v << 16; return x.f;
}
static __device__ __forceinline__ float bfhi(unsigned int v) {
    union { unsigned int u; float f; } x; x.u = v & 0xffff0000u; return x.f;
}

// ---------------- graph preprocessing ----------------

__global__ void zero_deg_kernel(int* __restrict__ deg) {
    int i = blockIdx.x * 256 + threadIdx.x;
    if (i < NR * NN) deg[i] = 0;
}

__global__ void count_deg_kernel(const int* __restrict__ edge_dst, int* __restrict__ deg) {
    int i = blockIdx.x * 256 + threadIdx.x;
    if (i < NR * NE) {
        int r = i / NE;
        atomicAdd(&deg[r * NN + edge_dst[i]], 1);
    }
}

__global__ __launch_bounds__(256) void scanA_kernel(const int* __restrict__ deg,
                                                    int* __restrict__ excl,
                                                    int* __restrict__ bsum) {
    const int r = blockIdx.x / NB_SCAN;
    const int b = blockIdx.x % NB_SCAN;
    const int tid = threadIdx.x;
    const int idx = b * 256 + tid;
    int v = (idx < NN) ? deg[r * NN + idx] : 0;
    __shared__ int buf[256];
    buf[tid] = v; __syncthreads();
    int sum = v;
    for (int off = 1; off < 256; off <<= 1) {
        int t = (tid >= off) ? buf[tid - off] : 0;
        __syncthreads();
        sum += t; buf[tid] = sum;
        __syncthreads();
    }
    if (idx < NN) excl[r * NN + idx] = sum - v;
    if (tid == 255) bsum[r * NB_SCAN + b] = sum;
}

__global__ __launch_bounds__(256) void scanB_kernel(int* __restrict__ bsum) {
    const int r = blockIdx.x;
    const int tid = threadIdx.x;
    int v = (tid < NB_SCAN) ? bsum[r * NB_SCAN + tid] : 0;
    __shared__ int buf[256];
    buf[tid] = v; __syncthreads();
    int sum = v;
    for (int off = 1; off < 256; off <<= 1) {
        int t = (tid >= off) ? buf[tid - off] : 0;
        __syncthreads();
        sum += t; buf[tid] = sum;
        __syncthreads();
    }
    if (tid < NB_SCAN) bsum[r * NB_SCAN + tid] = sum - v;
}

__global__ __launch_bounds__(256) void scanC_kernel(const int* __restrict__ excl,
                                                    const int* __restrict__ bsum,
                                                    int* __restrict__ row_start,
                                                    int* __restrict__ cursor) {
    const int r = blockIdx.x / NB_SCAN;
    const int b = blockIdx.x % NB_SCAN;
    const int idx = b * 256 + threadIdx.x;
    if (idx < NN) {
        int v = excl[r * NN + idx] + bsum[r * NB_SCAN + b];
        row_start[r * (NN + 1) + idx] = v;
        cursor[r * NN + idx] = v;
    }
    if (b == 0 && threadIdx.x == 0) row_start[r * (NN + 1) + NN] = NE;
}

__global__ void fill_csr_kernel(const int* __restrict__ edge_src,
                                const int* __restrict__ edge_dst,
                                int* __restrict__ cursor, int* __restrict__ csr_src) {
    int i = blockIdx.x * 256 + threadIdx.x;
    if (i < NR * NE) {
        int r = i / NE;
        int dst = edge_dst[i];
        int pos = atomicAdd(&cursor[r * NN + dst], 1);
        csr_src[r * NE + pos] = edge_src[i];
    }
}

__global__ void inv_deg_kernel(const int* __restrict__ deg, float* __restrict__ inv) {
    int i = blockIdx.x * 256 + threadIdx.x;
    if (i < NR * NN) inv[i] = 1.0f / fmaxf((float)deg[i], 1.0f);
}

// ---------------- weight / feature prep ----------------

__global__ void conv_feat_kernel(const float* __restrict__ f, unsigned short* __restrict__ h) {
    int i = (blockIdx.x * 256 + threadIdx.x) * 4;
    if (i < NN * HD) {
        h[i + 0] = f2bf(f[i + 0]);
        h[i + 1] = f2bf(f[i + 1]);
        h[i + 2] = f2bf(f[i + 2]);
        h[i + 3] = f2bf(f[i + 3]);
    }
}

// WtH [128 cols][640 k] bf16: k<128 -> Ws[k][c]; k=128+r*128+kk -> Wr[r][kk][c]
__global__ void prep_wh_kernel(const float* __restrict__ Ws, const float* __restrict__ Wr,
                               unsigned short* __restrict__ Wt) {
    int c = blockIdx.x;     // 128
    int k = threadIdx.x;    // 640
    float v;
    if (k < HD) v = Ws[k * HD + c];
    else {
        int r = (k - HD) >> 7, kk = (k - HD) & 127;
        v = Wr[(r * HD + kk) * HD + c];
    }
    Wt[c * (NR + 1) * HD + k] = f2bf(v);
}

// WtO [128 cols][640 k] bf16: cols >= 100 are zero
__global__ void prep_wo_kernel(const float* __restrict__ Ws, const float* __restrict__ Wr,
                               unsigned short* __restrict__ Wt) {
    int c = blockIdx.x;     // 128
    int k = threadIdx.x;    // 640
    float v = 0.0f;
    if (c < OD) {
        if (k < HD) v = Ws[k * OD + c];
        else {
            int r = (k - HD) >> 7, kk = (k - HD) & 127;
            v = Wr[(r * HD + kk) * OD + c];
        }
    }
    Wt[c * (NR + 1) * HD + k] = f2bf(v);
}

// ---------------- aggregation (gather-sum of raw h, scaled, bf16 out) ----------------
// agg[n][r*128 + j] = inv_deg[r][n] * sum_{e in csr(r,n)} h[src_e][j]
// one wave per (node, relation); 4 nodes per 1024-thread block.

__global__ __launch_bounds__(1024) void agg_kernel(const unsigned short* __restrict__ h,
                                                   const int* __restrict__ row_start,
                                                   const int* __restrict__ csr_src,
                                                   const float* __restrict__ inv_deg,
                                                   unsigned short* __restrict__ agg) {
    const int w = threadIdx.x >> 6;            // 0..15
    const int n = blockIdx.x * 4 + (w >> 2);
    const int r = w & 3;
    const int lane = threadIdx.x & 63;

    const int s = __builtin_amdgcn_readfirstlane(row_start[r * (NN + 1) + n]);
    const int e = __builtin_amdgcn_readfirstlane(row_start[r * (NN + 1) + n + 1]);

    const char* hb = (const char*)h + lane * 4;
    float s0 = 0.f, s1 = 0.f;
    int t = s;
    for (; t + 2 <= e; t += 2) {
        const int i0 = __builtin_amdgcn_readfirstlane(csr_src[r * NE + t]);
        const int i1 = __builtin_amdgcn_readfirstlane(csr_src[r * NE + t + 1]);
        unsigned int v0 = *(const unsigned int*)(hb + (size_t)i0 * 256);
        unsigned int v1 = *(const unsigned int*)(hb + (size_t)i1 * 256);
        s0 += bflo(v0) + bflo(v1);
        s1 += bfhi(v0) + bfhi(v1);
    }
    if (t < e) {
        const int i0 = __builtin_amdgcn_readfirstlane(csr_src[r * NE + t]);
        unsigned int v0 = *(const unsigned int*)(hb + (size_t)i0 * 256);
        s0 += bflo(v0);
        s1 += bfhi(v0);
    }
    const float wd = inv_deg[r * NN + n];
    unsigned int packed = (unsigned int)f2bf(wd * s0) | ((unsigned int)f2bf(wd * s1) << 16);
    *(unsigned int*)(agg + (size_t)n * 512 + r * 128 + lane * 2) = packed;
}

// ---------------- GEMM: out[M][128] = [h | agg][M][640] @ Wt[128][640]^T ----------------
// block: 256 thr = 4 waves (2 M x 2 N), tile 64(M) x 128(N), K=640 in 10 steps of 64.
// LDS: A dbuf 2x8KB @0, B dbuf 2x16KB @16KB. XOR swizzle (row&7)<<4 on both.
// MODE 0: bf16 + relu output via LDS bounce.  MODE 1: f32 direct output.

template<int MODE>
__global__ __launch_bounds__(256) void gemm_kernel(const unsigned short* __restrict__ h,
                                                   const unsigned short* __restrict__ agg,
                                                   const unsigned short* __restrict__ Bt,
                                                   void* __restrict__ outp, int M) {
    __shared__ __align__(16) char lds[49152];
    const int tid = threadIdx.x;
    const int m0 = blockIdx.x * MT;

    // staging chunk coords: A 512 chunks (2/thread), B 1024 chunks (4/thread)
    int aLds[2], aHoff[2], aGoff[2];
    int bLds[4], bGoff[4];
#pragma unroll
    for (int i = 0; i < 2; i++) {
        const int c = tid + i * 256;
        const int row = c >> 3, kb = (c & 7) * 16;
        int gr = m0 + row; if (gr >= M) gr = M - 1;
        aHoff[i] = gr * 256 + kb;              // byte into h   (+ ks*128)
        aGoff[i] = gr * 1024 + kb;             // byte into agg (+ (ks-2)*128)
        aLds[i] = row * 128 + (kb ^ ((row & 7) << 4));
    }
#pragma unroll
    for (int i = 0; i < 4; i++) {
        const int c = tid + i * 256;
        const int col = c >> 3, kb = (c & 7) * 16;
        bGoff[i] = col * 1280 + kb;            // byte into Bt (+ ks*128)
        bLds[i] = 16384 + col * 128 + (kb ^ ((col & 7) << 4));
    }

    const char* hB = (const char*)h;
    const char* aB = (const char*)agg;
    const char* bB = (const char*)Bt;

    int4v rA[2], rB[4];
    // prologue: stage ks=0
#pragma unroll
    for (int i = 0; i < 2; i++) rA[i] = *(const int4v*)(hB + aHoff[i]);
#pragma unroll
    for (int i = 0; i < 4; i++) rB[i] = *(const int4v*)(bB + bGoff[i]);
#pragma unroll
    for (int i = 0; i < 2; i++) *(int4v*)(lds + aLds[i]) = rA[i];
#pragma unroll
    for (int i = 0; i < 4; i++) *(int4v*)(lds + bLds[i]) = rB[i];
    __syncthreads();

    const int w = tid >> 6;
    const int lane = tid & 63;
    const int wm = (w & 1) * 32;
    const int wn = (w >> 1) * 64;
    const int lr = lane & 15;
    const int lg = lane >> 4;

    // fragment LDS offsets [idx][ksub]
    int aF[2][2], bF[4][2];
#pragma unroll
    for (int mi = 0; mi < 2; mi++)
#pragma unroll
        for (int ksub = 0; ksub < 2; ksub++) {
            const int row = wm + mi * 16 + lr;
            const int kb = ksub * 64 + lg * 16;
            aF[mi][ksub] = row * 128 + (kb ^ ((row & 7) << 4));
        }
#pragma unroll
    for (int ni = 0; ni < 4; ni++)
#pragma unroll
        for (int ksub = 0; ksub < 2; ksub++) {
            const int col = wn + ni * 16 + lr;
            const int kb = ksub * 64 + lg * 16;
            bF[ni][ksub] = 16384 + col * 128 + (kb ^ ((col & 7) << 4));
        }

    f32x4 acc[2][4];
#pragma unroll
    for (int mi = 0; mi < 2; mi++)
#pragma unroll
        for (int ni = 0; ni < 4; ni++) acc[mi][ni] = (f32x4){0.f, 0.f, 0.f, 0.f};

#pragma unroll
    for (int ks = 0; ks < KSTEPS; ++ks) {
        const int aoff = (ks & 1) * 8192;
        const int boff = (ks & 1) * 16384;
        // issue next-tile global loads early (latency hides under MFMA)
        if (ks + 1 < KSTEPS) {
            const int ksn = ks + 1;
            if (ksn < 2) {
#pragma unroll
                for (int i = 0; i < 2; i++) rA[i] = *(const int4v*)(hB + aHoff[i] + ksn * 128);
            } else {
#pragma unroll
                for (int i = 0; i < 2; i++) rA[i] = *(const int4v*)(aB + aGoff[i] + (ksn - 2) * 128);
            }
#pragma unroll
            for (int i = 0; i < 4; i++) rB[i] = *(const int4v*)(bB + bGoff[i] + ksn * 128);
        }
        // compute current buffer
#pragma unroll
        for (int ksub = 0; ksub < 2; ++ksub) {
            bf16x8 af[2], bfr[4];
#pragma unroll
            for (int mi = 0; mi < 2; mi++) af[mi] = *(const bf16x8*)(lds + aoff + aF[mi][ksub]);
#pragma unroll
            for (int ni = 0; ni < 4; ni++) bfr[ni] = *(const bf16x8*)(lds + boff + bF[ni][ksub]);
#pragma unroll
            for (int mi = 0; mi < 2; mi++)
#pragma unroll
                for (int ni = 0; ni < 4; ni++)
                    acc[mi][ni] = __builtin_amdgcn_mfma_f32_16x16x32_bf16(af[mi], bfr[ni], acc[mi][ni], 0, 0, 0);
        }
        __syncthreads();                    // all waves done reading buf before overwrite
        if (ks + 1 < KSTEPS) {
            const int na = ((ks + 1) & 1) * 8192;
            const int nb = ((ks + 1) & 1) * 16384;
#pragma unroll
            for (int i = 0; i < 2; i++) *(int4v*)(lds + na + aLds[i]) = rA[i];
#pragma unroll
            for (int i = 0; i < 4; i++) *(int4v*)(lds + nb + bLds[i]) = rB[i];
            __syncthreads();                // new buf visible
        }
    }

    if (MODE == 0) {
        // bounce tile [64][128] bf16 at lds[0..16384), then coalesced 16B stores
#pragma unroll
        for (int mi = 0; mi < 2; mi++)
#pragma unroll
            for (int ni = 0; ni < 4; ni++) {
                const int col = wn + ni * 16 + lr;
#pragma unroll
                for (int j = 0; j < 4; j++) {
                    const int row = wm + mi * 16 + lg * 4 + j;
                    *(unsigned short*)(lds + row * 256 + col * 2) = f2bf(fmaxf(acc[mi][ni][j], 0.f));
                }
            }
        __syncthreads();
        unsigned short* o = (unsigned short*)outp;
#pragma unroll
        for (int c = tid; c < 1024; c += 256) {
            const int row = c >> 4, kb = (c & 15) * 16;
            const int grow = m0 + row;
            if (grow < M)
                *(int4v*)((char*)(o + (size_t)grow * 128) + kb) = *(const int4v*)(lds + row * 256 + kb);
        }
    } else {
        float* o = (float*)outp;
#pragma unroll
        for (int mi = 0; mi < 2; mi++)
#pragma unroll
            for (int ni = 0; ni < 4; ni++) {
                const int col = wn + ni * 16 + lr;
#pragma unroll
                for (int j = 0; j < 4; j++) {
                    const int row = m0 + wm + mi * 16 + lg * 4 + j;
                    if (row < M) o[(size_t)row * 128 + col] = acc[mi][ni][j];
                }
            }
    }
}

// ---------------- final gather (float4) ----------------

__global__ __launch_bounds__(256) void gather_out_kernel(const float* __restrict__ hOut,
                                                         const int* __restrict__ head,
                                                         const int* __restrict__ tail,
                                                         float* __restrict__ out) {
    const int gid = blockIdx.x * 256 + threadIdx.x;
    const int q = gid >> 5, c = gid & 31;
    if (q >= 2 * NQ || c >= 25) return;
    const int node = (q < NQ) ? head[q] : tail[q - NQ];
    f32x4 v = *(const f32x4*)(hOut + (size_t)node * 128 + c * 4);
    *(f32x4*)(out + (size_t)q * OD + c * 4) = v;
}

// ---------------- launch ----------------

extern "C" void kernel_launch(void* const* d_in, const int* in_sizes, int n_in,
                              void* d_out, int out_size, void* d_ws, size_t ws_size,
                              hipStream_t stream) {
    const float* feature = (const float*)d_in[0];
    const float* Wr_h    = (const float*)d_in[1];   // [2][4][128][128]
    const float* Ws_h    = (const float*)d_in[2];   // [2][128][128]
    const float* Wr_o    = (const float*)d_in[3];   // [4][128][100]
    const float* Ws_o    = (const float*)d_in[4];   // [128][100]
    const int* edge_src  = (const int*)d_in[5];
    const int* edge_dst  = (const int*)d_in[6];
    const int* head_idx  = (const int*)d_in[7];
    const int* tail_idx  = (const int*)d_in[8];
    float* out = (float*)d_out;

    char* ws = (char*)d_ws;
    size_t off = 0;
    auto alloc = [&](size_t bytes) -> void* {
        void* p = ws + off;
        off += (bytes + 255) & ~(size_t)255;
        return p;
    };
    unsigned short* agg  = (unsigned short*)alloc((size_t)NN * 512 * 2);
    unsigned short* hA   = (unsigned short*)alloc((size_t)NN * HD * 2);
    unsigned short* hB   = (unsigned short*)alloc((size_t)NN * HD * 2);
    float*          hOut = (float*)alloc((size_t)NN * 128 * 4);
    unsigned short* WtH0 = (unsigned short*)alloc(128 * 640 * 2);
    unsigned short* WtH1 = (unsigned short*)alloc(128 * 640 * 2);
    unsigned short* WtO  = (unsigned short*)alloc(128 * 640 * 2);
    int*            deg  = (int*)alloc((size_t)NR * NN * 4);
    float*          inv  = (float*)alloc((size_t)NR * NN * 4);
    int*            rowS = (int*)alloc((size_t)NR * (NN + 1) * 4);
    int*            curs = (int*)alloc((size_t)NR * NN * 4);
    int*            csrS = (int*)alloc((size_t)NR * NE * 4);
    int*            excl = (int*)alloc((size_t)NR * NN * 4);
    int*            bsum = (int*)alloc((size_t)NR * NB_SCAN * 4);
    (void)ws_size;

    // graph prep
    zero_deg_kernel<<<(NR * NN + 255) / 256, 256, 0, stream>>>(deg);
    count_deg_kernel<<<(NR * NE + 255) / 256, 256, 0, stream>>>(edge_dst, deg);
    scanA_kernel<<<NR * NB_SCAN, 256, 0, stream>>>(deg, excl, bsum);
    scanB_kernel<<<NR, 256, 0, stream>>>(bsum);
    scanC_kernel<<<NR * NB_SCAN, 256, 0, stream>>>(excl, bsum, rowS, curs);
    fill_csr_kernel<<<(NR * NE + 255) / 256, 256, 0, stream>>>(edge_src, edge_dst, curs, csrS);
    inv_deg_kernel<<<(NR * NN + 255) / 256, 256, 0, stream>>>(deg, inv);

    // weight / feature prep
    conv_feat_kernel<<<(NN * HD / 4 + 255) / 256, 256, 0, stream>>>(feature, hA);
    prep_wh_kernel<<<128, 640, 0, stream>>>(Ws_h, Wr_h, WtH0);
    prep_wh_kernel<<<128, 640, 0, stream>>>(Ws_h + HD * HD, Wr_h + NR * HD * HD, WtH1);
    prep_wo_kernel<<<128, 640, 0, stream>>>(Ws_o, Wr_o, WtO);

    const int gblocks = (NN + MT - 1) / MT;   // 782

    // layer 0: hA --agg--> agg ; [hA|agg] @ WtH0 -> hB (relu, bf16)
    agg_kernel<<<NN / 4, 1024, 0, stream>>>(hA, rowS, csrS, inv, agg);
    gemm_kernel<0><<<gblocks, 256, 0, stream>>>(hA, agg, WtH0, hB, NN);

    // layer 1
    agg_kernel<<<NN / 4, 1024, 0, stream>>>(hB, rowS, csrS, inv, agg);
    gemm_kernel<0><<<gblocks, 256, 0, stream>>>(hB, agg, WtH1, hA, NN);

    // output layer
    agg_kernel<<<NN / 4, 1024, 0, stream>>>(hA, rowS, csrS, inv, agg);
    gemm_kernel<1><<<gblocks, 256, 0, stream>>>(hA, agg, WtO, hOut, NN);

    // final gather
    gather_out_kernel<<<(2 * NQ * 32 + 255) / 256, 256, 0, stream>>>(hOut, head_idx, tail_idx, out);
}